// Round 6
// baseline (191.527 us; speedup 1.0000x reference)
//
#include <hip/hip_runtime.h>

#define N 8192
#define Dk 128
#define EPSC 1e-6f
#define MARGIN 0.2f

typedef __attribute__((ext_vector_type(8))) short bf16x8;
typedef __attribute__((ext_vector_type(4))) float f32x4;

__device__ __forceinline__ unsigned short f2bf(float f) {
    unsigned u = __float_as_uint(f);
    u = (u + 0x7FFFu + ((u >> 16) & 1u)) >> 16;  // RNE fp32->bf16
    return (unsigned short)u;
}

// Kernel A: pack x into MFMA-fragment order (bf16) + per-row P / QT(-Q/2, class).
// Frag uint4 index F(rt,kk,lane) = (rt*4+kk)*64 + lane: lane q*16+n holds chunk
// (q+4*kk) (8 bf16) of row rt*16+n. Wave handles 4 rows: lane -> row r0+(lane>>4),
// chunk c = lane&15. No stat init needed (main writes partials unconditionally).
__global__ void prep_kernel(const float* __restrict__ x, const int* __restrict__ tgt,
                            uint4* __restrict__ Frag, uint2* __restrict__ QT,
                            float* __restrict__ P) {
    int wv = blockIdx.x * 4 + (threadIdx.x >> 6);
    int lane = threadIdx.x & 63;
    int row = wv * 4 + (lane >> 4);
    int c = lane & 15;
    const float4* x4 = reinterpret_cast<const float4*>(x);
    float4 v0 = x4[row * 32 + c * 2];
    float4 v1 = x4[row * 32 + c * 2 + 1];
    float sq = v0.x * v0.x + v0.y * v0.y + v0.z * v0.z + v0.w * v0.w +
               v1.x * v1.x + v1.y * v1.y + v1.z * v1.z + v1.w * v1.w;
    float s = v0.x + v0.y + v0.z + v0.w + v1.x + v1.y + v1.z + v1.w;
    ushort4 lo, hi;
    lo.x = f2bf(v0.x); lo.y = f2bf(v0.y); lo.z = f2bf(v0.z); lo.w = f2bf(v0.w);
    hi.x = f2bf(v1.x); hi.y = f2bf(v1.y); hi.z = f2bf(v1.z); hi.w = f2bf(v1.w);
    uint4 pk;
    pk.x = (unsigned)lo.x | ((unsigned)lo.y << 16);
    pk.y = (unsigned)lo.z | ((unsigned)lo.w << 16);
    pk.z = (unsigned)hi.x | ((unsigned)hi.y << 16);
    pk.w = (unsigned)hi.z | ((unsigned)hi.w << 16);
    Frag[((row >> 4) * 4 + (c >> 2)) * 64 + (c & 3) * 16 + (row & 15)] = pk;
    // reduce sq,s across the 16 chunk-lanes of this row (xor masks stay in-group)
#pragma unroll
    for (int m = 1; m <= 8; m <<= 1) {
        sq += __shfl_xor(sq, m);
        s += __shfl_xor(s, m);
    }
    if (c == 0) {
        P[row] = sq - 2.0f * EPSC * s;
        float Qj = sq + 2.0f * EPSC * s + (float)Dk * EPSC * EPSC;
        uint2 qt;
        qt.x = __float_as_uint(-0.5f * Qj);
        qt.y = (unsigned)tgt[row];
        QT[row] = qt;
    }
}

// Kernel B: NO LDS, NO barriers, NO atomics. Grid = 128 i-groups x 8 j-groups.
// Block = 64 anchors, 4 waves; wave w streams 16 j-tiles (16 cols each) of its own
// j-strip, B-fragments loaded COALESCED from fragment-packed Frag (L2-resident),
// double-buffered in registers. Af (64 rows x K128) persistent in registers.
// acc init = -Q_j/2 => acc = dot - Q_j/2; d2 = P_i - 2*acc (monotone decreasing):
// hardest_pos = min acc over same-class, hardest_neg = max acc over diff-class.
// Stats committed as plain stores to part[jg*4+w][i]; finish reduces 32 partials.
__global__ __launch_bounds__(256, 3) void main_kernel(
        const uint4* __restrict__ Frag, const uint2* __restrict__ QT,
        const int* __restrict__ tgt,
        float* __restrict__ partHp, float* __restrict__ partMn) {
    const int w = threadIdx.x >> 6;
    const int lane = threadIdx.x & 63;
    const int n = lane & 15;
    const int q = lane >> 4;

    const int ig = (int)blockIdx.x >> 3;  // 0..127
    const int jg = (int)blockIdx.x & 7;   // 0..7
    const int rbase = ig * 64;
    const int jt0 = jg * 64 + w * 16;     // this wave's 16 j-tiles

    const bf16x8* Fr = reinterpret_cast<const bf16x8*>(Frag);

    // Persistent A fragments: 64 rows x K=128 (64 VGPRs), coalesced loads
    bf16x8 Af[4][4];
#pragma unroll
    for (int ti = 0; ti < 4; ++ti)
#pragma unroll
        for (int kk = 0; kk < 4; ++kk)
            Af[ti][kk] = Fr[((ig * 4 + ti) * 4 + kk) * 64 + lane];

    // anchor classes for this lane's 16 row-slots: row = rbase + 16*ti + 4*q + r
    int tsl[16];
#pragma unroll
    for (int ti = 0; ti < 4; ++ti) {
        int4 t4 = *reinterpret_cast<const int4*>(&tgt[rbase + 16 * ti + 4 * q]);
        tsl[4 * ti + 0] = t4.x;
        tsl[4 * ti + 1] = t4.y;
        tsl[4 * ti + 2] = t4.z;
        tsl[4 * ti + 3] = t4.w;
    }

    float hp[16], mn[16];
#pragma unroll
    for (int s = 0; s < 16; ++s) {
        hp[s] = INFINITY;   // min over same-class acc
        mn[s] = -INFINITY;  // max over diff-class acc
    }

    bf16x8 B0[4], B1[4];
    uint2 q0, q1;

    auto loadB = [&](bf16x8* B, uint2& qt, int t) {
        const int jt = jt0 + t;
#pragma unroll
        for (int kk = 0; kk < 4; ++kk) B[kk] = Fr[(jt * 4 + kk) * 64 + lane];
        qt = QT[jt * 16 + n];
    };

    auto compute = [&](const bf16x8* B, uint2 qt) {
        const float Qv = __uint_as_float(qt.x);  // = -Q_j/2
        const int tv = (int)qt.y;
        f32x4 acc[4];
#pragma unroll
        for (int ti = 0; ti < 4; ++ti) acc[ti] = Qv;
#pragma unroll
        for (int kk = 0; kk < 4; ++kk)
#pragma unroll
            for (int ti = 0; ti < 4; ++ti)
                acc[ti] = __builtin_amdgcn_mfma_f32_16x16x32_bf16(Af[ti][kk], B[kk],
                                                                  acc[ti], 0, 0, 0);
        // acc elem r is (row rbase+16ti+4q+r, col jt*16+n), value dot - Q_j/2
#pragma unroll
        for (int ti = 0; ti < 4; ++ti) {
            f32x4 v = acc[ti];
            int e0 = tv == tsl[4 * ti + 0];
            int e1 = tv == tsl[4 * ti + 1];
            int e2 = tv == tsl[4 * ti + 2];
            int e3 = tv == tsl[4 * ti + 3];
            if (__ballot(e0 | e1 | e2 | e3)) {  // tile has same-class pairs (~23%)
                hp[4 * ti + 0] = fminf(hp[4 * ti + 0], e0 ? v[0] : INFINITY);
                hp[4 * ti + 1] = fminf(hp[4 * ti + 1], e1 ? v[1] : INFINITY);
                hp[4 * ti + 2] = fminf(hp[4 * ti + 2], e2 ? v[2] : INFINITY);
                hp[4 * ti + 3] = fminf(hp[4 * ti + 3], e3 ? v[3] : INFINITY);
                mn[4 * ti + 0] = fmaxf(mn[4 * ti + 0], e0 ? -INFINITY : v[0]);
                mn[4 * ti + 1] = fmaxf(mn[4 * ti + 1], e1 ? -INFINITY : v[1]);
                mn[4 * ti + 2] = fmaxf(mn[4 * ti + 2], e2 ? -INFINITY : v[2]);
                mn[4 * ti + 3] = fmaxf(mn[4 * ti + 3], e3 ? -INFINITY : v[3]);
            } else {  // all-negative tile fast path
                mn[4 * ti + 0] = fmaxf(mn[4 * ti + 0], v[0]);
                mn[4 * ti + 1] = fmaxf(mn[4 * ti + 1], v[1]);
                mn[4 * ti + 2] = fmaxf(mn[4 * ti + 2], v[2]);
                mn[4 * ti + 3] = fmaxf(mn[4 * ti + 3], v[3]);
            }
        }
    };

    loadB(B0, q0, 0);
#pragma unroll
    for (int tt = 0; tt < 16; tt += 2) {
        if (tt + 1 < 16) loadB(B1, q1, tt + 1);  // prefetch while computing tt
        compute(B0, q0);
        if (tt + 2 < 16) loadB(B0, q0, tt + 2);  // prefetch while computing tt+1
        if (tt + 1 < 16) compute(B1, q1);
    }

    // reduce across the 16 col-lanes; lanes n==0 commit rows 16ti+4q+r
#pragma unroll
    for (int m = 1; m <= 8; m <<= 1) {
#pragma unroll
        for (int s = 0; s < 16; ++s) {
            hp[s] = fminf(hp[s], __shfl_xor(hp[s], m));
            mn[s] = fmaxf(mn[s], __shfl_xor(mn[s], m));
        }
    }
    if (n == 0) {
        const int wg = jg * 4 + w;
#pragma unroll
        for (int ti = 0; ti < 4; ++ti)
#pragma unroll
            for (int r = 0; r < 4; ++r) {
                int i = rbase + 16 * ti + 4 * q + r;
                partHp[wg * N + i] = hp[4 * ti + r];
                partMn[wg * N + i] = mn[4 * ti + r];
            }
    }
}

// Kernel C: single block; reduce 32 partials per row, then loss + mean
__global__ void finish_kernel(const float* __restrict__ P,
                              const float* __restrict__ partHp,
                              const float* __restrict__ partMn,
                              float* __restrict__ out) {
    int t = threadIdx.x;  // 1024 threads
    float sum = 0.0f;
#pragma unroll
    for (int k = 0; k < 8; ++k) {
        int i = t + 1024 * k;
        float hpm = INFINITY, mnm = -INFINITY;
#pragma unroll
        for (int wg = 0; wg < 32; ++wg) {
            hpm = fminf(hpm, partHp[wg * N + i]);
            mnm = fmaxf(mnm, partMn[wg * N + i]);
        }
        float Pi = P[i];
        float hp = sqrtf(fmaxf(fmaf(-2.0f, hpm, Pi), 0.0f));
        float hn = sqrtf(fmaxf(fmaf(-2.0f, mnm, Pi), 0.0f));
        sum += fmaxf(hp - hn + MARGIN, 0.0f);
    }
#pragma unroll
    for (int m = 32; m >= 1; m >>= 1) sum += __shfl_xor(sum, m);
    __shared__ float ws[16];
    if ((t & 63) == 0) ws[t >> 6] = sum;
    __syncthreads();
    if (t == 0) {
        float tot = 0.0f;
#pragma unroll
        for (int i = 0; i < 16; ++i) tot += ws[i];
        out[0] = tot * (1.0f / (float)N);
    }
}

extern "C" void kernel_launch(void* const* d_in, const int* in_sizes, int n_in,
                              void* d_out, int out_size, void* d_ws, size_t ws_size,
                              hipStream_t stream) {
    const float* x = (const float*)d_in[0];
    const int* tgt = (const int*)d_in[1];
    float* out = (float*)d_out;

    char* ws = (char*)d_ws;
    const size_t frag_b = (size_t)N * Dk * 2;  // 2 MB fragment-packed bf16
    uint4* Frag = (uint4*)ws;
    uint2* QT = (uint2*)(ws + frag_b);
    float* P = (float*)(ws + frag_b + (size_t)N * 8);
    float* partHp = (float*)(ws + frag_b + (size_t)N * 12);
    float* partMn = (float*)(ws + frag_b + (size_t)N * 12 + (size_t)32 * N * 4);

    prep_kernel<<<N / 16, 256, 0, stream>>>(x, tgt, Frag, QT, P);
    main_kernel<<<1024, 256, 0, stream>>>(Frag, QT, tgt, partHp, partMn);
    finish_kernel<<<1, 1024, 0, stream>>>(P, partHp, partMn, out);
}

// Round 7
// 101.951 us; speedup vs baseline: 1.8786x; 1.8786x over previous
//
#include <hip/hip_runtime.h>

#define N 8192
#define Dk 128
#define EPSC 1e-6f
#define MARGIN 0.2f

typedef __attribute__((ext_vector_type(8))) short bf16x8;
typedef __attribute__((ext_vector_type(4))) float f32x4;

__device__ __forceinline__ unsigned short f2bf(float f) {
    unsigned u = __float_as_uint(f);
    u = (u + 0x7FFFu + ((u >> 16) & 1u)) >> 16;  // RNE fp32->bf16
    return (unsigned short)u;
}

// Kernel A: pack x into MFMA-fragment order (bf16) + per-row P / QT(-Q/2, class).
// Frag uint4 index F(rt,kk,lane) = (rt*4+kk)*64 + lane: lane q*16+n holds chunk
// (q+4*kk) (8 bf16) of row rt*16+n. (verified R6: absmax 0.0)
__global__ void prep_kernel(const float* __restrict__ x, const int* __restrict__ tgt,
                            uint4* __restrict__ Frag, uint2* __restrict__ QT,
                            float* __restrict__ P) {
    int wv = blockIdx.x * 4 + (threadIdx.x >> 6);
    int lane = threadIdx.x & 63;
    int row = wv * 4 + (lane >> 4);
    int c = lane & 15;
    const float4* x4 = reinterpret_cast<const float4*>(x);
    float4 v0 = x4[row * 32 + c * 2];
    float4 v1 = x4[row * 32 + c * 2 + 1];
    float sq = v0.x * v0.x + v0.y * v0.y + v0.z * v0.z + v0.w * v0.w +
               v1.x * v1.x + v1.y * v1.y + v1.z * v1.z + v1.w * v1.w;
    float s = v0.x + v0.y + v0.z + v0.w + v1.x + v1.y + v1.z + v1.w;
    ushort4 lo, hi;
    lo.x = f2bf(v0.x); lo.y = f2bf(v0.y); lo.z = f2bf(v0.z); lo.w = f2bf(v0.w);
    hi.x = f2bf(v1.x); hi.y = f2bf(v1.y); hi.z = f2bf(v1.z); hi.w = f2bf(v1.w);
    uint4 pk;
    pk.x = (unsigned)lo.x | ((unsigned)lo.y << 16);
    pk.y = (unsigned)lo.z | ((unsigned)lo.w << 16);
    pk.z = (unsigned)hi.x | ((unsigned)hi.y << 16);
    pk.w = (unsigned)hi.z | ((unsigned)hi.w << 16);
    Frag[((row >> 4) * 4 + (c >> 2)) * 64 + (c & 3) * 16 + (row & 15)] = pk;
#pragma unroll
    for (int m = 1; m <= 8; m <<= 1) {
        sq += __shfl_xor(sq, m);
        s += __shfl_xor(s, m);
    }
    if (c == 0) {
        P[row] = sq - 2.0f * EPSC * s;
        float Qj = sq + 2.0f * EPSC * s + (float)Dk * EPSC * EPSC;
        uint2 qt;
        qt.x = __float_as_uint(-0.5f * Qj);
        qt.y = (unsigned)tgt[row];
        QT[row] = qt;
    }
}

// load j-tile t's B fragments (coalesced 1 KB per instr) + its QT pair
#define LOADB(Bb, qq, t)                              \
    do {                                              \
        const int jt_ = jt0 + (t);                    \
        Bb[0] = Fr[(jt_ * 4 + 0) * 64 + lane];        \
        Bb[1] = Fr[(jt_ * 4 + 1) * 64 + lane];        \
        Bb[2] = Fr[(jt_ * 4 + 2) * 64 + lane];        \
        Bb[3] = Fr[(jt_ * 4 + 3) * 64 + lane];        \
        qq = QT[jt_ * 16 + n];                        \
    } while (0)

// 16 MFMAs vs one j-tile + masked min/max epilogue (straight-line, no lambdas!)
#define COMPUTE(Bb, qq)                                                               \
    do {                                                                              \
        const float Qv_ = __uint_as_float(qq.x); /* = -Q_j/2 */                       \
        const int tv_ = (int)qq.y;                                                    \
        f32x4 acc[4];                                                                 \
        acc[0] = Qv_; acc[1] = Qv_; acc[2] = Qv_; acc[3] = Qv_;                       \
        _Pragma("unroll")                                                             \
        for (int kk = 0; kk < 4; ++kk) {                                              \
            _Pragma("unroll")                                                         \
            for (int ti = 0; ti < 4; ++ti)                                            \
                acc[ti] = __builtin_amdgcn_mfma_f32_16x16x32_bf16(Af[ti][kk], Bb[kk], \
                                                                  acc[ti], 0, 0, 0);  \
        }                                                                             \
        _Pragma("unroll")                                                             \
        for (int ti = 0; ti < 4; ++ti) {                                              \
            f32x4 v = acc[ti];                                                        \
            int e0 = tv_ == tsl[4 * ti + 0];                                          \
            int e1 = tv_ == tsl[4 * ti + 1];                                          \
            int e2 = tv_ == tsl[4 * ti + 2];                                          \
            int e3 = tv_ == tsl[4 * ti + 3];                                          \
            if (__ballot(e0 | e1 | e2 | e3)) {                                        \
                hp[4 * ti + 0] = fminf(hp[4 * ti + 0], e0 ? v[0] : INFINITY);         \
                hp[4 * ti + 1] = fminf(hp[4 * ti + 1], e1 ? v[1] : INFINITY);         \
                hp[4 * ti + 2] = fminf(hp[4 * ti + 2], e2 ? v[2] : INFINITY);         \
                hp[4 * ti + 3] = fminf(hp[4 * ti + 3], e3 ? v[3] : INFINITY);         \
                mn[4 * ti + 0] = fmaxf(mn[4 * ti + 0], e0 ? -INFINITY : v[0]);        \
                mn[4 * ti + 1] = fmaxf(mn[4 * ti + 1], e1 ? -INFINITY : v[1]);        \
                mn[4 * ti + 2] = fmaxf(mn[4 * ti + 2], e2 ? -INFINITY : v[2]);        \
                mn[4 * ti + 3] = fmaxf(mn[4 * ti + 3], e3 ? -INFINITY : v[3]);        \
            } else {                                                                  \
                mn[4 * ti + 0] = fmaxf(mn[4 * ti + 0], v[0]);                         \
                mn[4 * ti + 1] = fmaxf(mn[4 * ti + 1], v[1]);                         \
                mn[4 * ti + 2] = fmaxf(mn[4 * ti + 2], v[2]);                         \
                mn[4 * ti + 3] = fmaxf(mn[4 * ti + 3], v[3]);                         \
            }                                                                         \
        }                                                                             \
    } while (0)

// Kernel B: NO LDS, NO barriers, NO atomics. Grid = 128 i-groups x 8 j-groups.
// Wave w streams 16 j-tiles of its own strip; B fragments coalesced from
// fragment-packed Frag (L2-resident), 4-deep register pipeline (~3 computes of
// prefetch distance). Af (64 rows x K128) persistent. acc init = -Q_j/2 =>
// acc = dot - Q_j/2; d2 = P_i - 2*acc (monotone decreasing): hardest_pos = min
// acc over same-class, hardest_neg = max acc over diff-class.
__global__ __launch_bounds__(256, 2) void main_kernel(
        const uint4* __restrict__ Frag, const uint2* __restrict__ QT,
        const int* __restrict__ tgt,
        float* __restrict__ partHp, float* __restrict__ partMn) {
    const int w = threadIdx.x >> 6;
    const int lane = threadIdx.x & 63;
    const int n = lane & 15;
    const int q = lane >> 4;

    const int ig = (int)blockIdx.x >> 3;  // 0..127
    const int jg = (int)blockIdx.x & 7;   // 0..7
    const int rbase = ig * 64;
    const int jt0 = jg * 64 + w * 16;     // this wave's 16 j-tiles

    const bf16x8* Fr = reinterpret_cast<const bf16x8*>(Frag);

    // Persistent A fragments: 64 rows x K=128 (64 VGPRs), coalesced loads
    bf16x8 Af[4][4];
#pragma unroll
    for (int ti = 0; ti < 4; ++ti)
#pragma unroll
        for (int kk = 0; kk < 4; ++kk)
            Af[ti][kk] = Fr[((ig * 4 + ti) * 4 + kk) * 64 + lane];

    int tsl[16];
#pragma unroll
    for (int ti = 0; ti < 4; ++ti) {
        int4 t4 = *reinterpret_cast<const int4*>(&tgt[rbase + 16 * ti + 4 * q]);
        tsl[4 * ti + 0] = t4.x;
        tsl[4 * ti + 1] = t4.y;
        tsl[4 * ti + 2] = t4.z;
        tsl[4 * ti + 3] = t4.w;
    }

    float hp[16], mn[16];
#pragma unroll
    for (int s = 0; s < 16; ++s) {
        hp[s] = INFINITY;   // min over same-class acc
        mn[s] = -INFINITY;  // max over diff-class acc
    }

    bf16x8 Ba[4], Bb[4], Bc[4], Bd[4];
    uint2 qa, qb, qc, qd;

    LOADB(Ba, qa, 0);
    LOADB(Bb, qb, 1);
    LOADB(Bc, qc, 2);
    LOADB(Bd, qd, 3);
#pragma unroll
    for (int tt = 0; tt < 16; tt += 4) {
        COMPUTE(Ba, qa);
        if (tt < 12) LOADB(Ba, qa, tt + 4);
        COMPUTE(Bb, qb);
        if (tt < 12) LOADB(Bb, qb, tt + 5);
        COMPUTE(Bc, qc);
        if (tt < 12) LOADB(Bc, qc, tt + 6);
        COMPUTE(Bd, qd);
        if (tt < 12) LOADB(Bd, qd, tt + 7);
    }

    // reduce across the 16 col-lanes; lanes n==0 commit rows 16ti+4q+r
#pragma unroll
    for (int m = 1; m <= 8; m <<= 1) {
#pragma unroll
        for (int s = 0; s < 16; ++s) {
            hp[s] = fminf(hp[s], __shfl_xor(hp[s], m));
            mn[s] = fmaxf(mn[s], __shfl_xor(mn[s], m));
        }
    }
    if (n == 0) {
        const int wg = jg * 4 + w;
#pragma unroll
        for (int ti = 0; ti < 4; ++ti)
#pragma unroll
            for (int r = 0; r < 4; ++r) {
                int i = rbase + 16 * ti + 4 * q + r;
                partHp[wg * N + i] = hp[4 * ti + r];
                partMn[wg * N + i] = mn[4 * ti + r];
            }
    }
}

// Kernel C: 32 blocks x 256 threads; thread t of block b owns anchor i = b*256+t.
// Reduce 32 partials, per-anchor loss, block-reduce, one atomicAdd per block.
__global__ void finish_kernel(const float* __restrict__ P,
                              const float* __restrict__ partHp,
                              const float* __restrict__ partMn,
                              float* __restrict__ out) {
    int i = blockIdx.x * 256 + threadIdx.x;
    float hpm = INFINITY, mnm = -INFINITY;
#pragma unroll
    for (int wg = 0; wg < 32; ++wg) {
        hpm = fminf(hpm, partHp[wg * N + i]);
        mnm = fmaxf(mnm, partMn[wg * N + i]);
    }
    float Pi = P[i];
    float hp = sqrtf(fmaxf(fmaf(-2.0f, hpm, Pi), 0.0f));
    float hn = sqrtf(fmaxf(fmaf(-2.0f, mnm, Pi), 0.0f));
    float sum = fmaxf(hp - hn + MARGIN, 0.0f) * (1.0f / (float)N);
#pragma unroll
    for (int m = 32; m >= 1; m >>= 1) sum += __shfl_xor(sum, m);
    __shared__ float ws[4];
    int lane = threadIdx.x & 63, wv = threadIdx.x >> 6;
    if (lane == 0) ws[wv] = sum;
    __syncthreads();
    if (threadIdx.x == 0) atomicAdd(out, ws[0] + ws[1] + ws[2] + ws[3]);
}

extern "C" void kernel_launch(void* const* d_in, const int* in_sizes, int n_in,
                              void* d_out, int out_size, void* d_ws, size_t ws_size,
                              hipStream_t stream) {
    const float* x = (const float*)d_in[0];
    const int* tgt = (const int*)d_in[1];
    float* out = (float*)d_out;

    char* ws = (char*)d_ws;
    const size_t frag_b = (size_t)N * Dk * 2;  // 2 MB fragment-packed bf16
    uint4* Frag = (uint4*)ws;
    uint2* QT = (uint2*)(ws + frag_b);
    float* P = (float*)(ws + frag_b + (size_t)N * 8);
    float* partHp = (float*)(ws + frag_b + (size_t)N * 12);
    float* partMn = (float*)(ws + frag_b + (size_t)N * 12 + (size_t)32 * N * 4);

    hipMemsetAsync(d_out, 0, sizeof(float), stream);
    prep_kernel<<<N / 16, 256, 0, stream>>>(x, tgt, Frag, QT, P);
    main_kernel<<<1024, 256, 0, stream>>>(Frag, QT, tgt, partHp, partMn);
    finish_kernel<<<32, 256, 0, stream>>>(P, partHp, partMn, out);
}